// Round 4
// baseline (105.956 us; speedup 1.0000x reference)
//
#include <hip/hip_runtime.h>
#include <cstdint>
#include <cstddef>

#define TPB 256
#define EPT 8             // float4s per thread in focal kernel

// ---------------------------------------------------------------------------
// Kernel 0: prep per-image target tables (B*T entries, trivial).
// ta = (tl0,tl1,br0,br1), tb = (c0,c1,s0,s1), tc = (area, cls_as_float)
// ---------------------------------------------------------------------------
__global__ void prep_kernel(const float* __restrict__ bbox_tgts,  // [B,T,4] tlbr
                            const int*   __restrict__ clas_tgts,  // [B,T]
                            int BT,
                            float4* __restrict__ ta_tab,
                            float4* __restrict__ tb_tab,
                            float2* __restrict__ tc_tab)
{
    const int i = blockIdx.x * blockDim.x + threadIdx.x;
    if (i < BT) {
        const float4 tg = reinterpret_cast<const float4*>(bbox_tgts)[i];
        // tlbr -> cthw (as reference), then cthw -> tlbr for IoU (same op order)
        const float c0 = (tg.x + tg.z) * 0.5f, c1 = (tg.y + tg.w) * 0.5f;
        const float s0 = tg.z - tg.x,          s1 = tg.w - tg.y;
        ta_tab[i] = make_float4(c0 - s0 * 0.5f, c1 - s1 * 0.5f,
                                c0 + s0 * 0.5f, c1 + s1 * 0.5f);
        tb_tab[i] = make_float4(c0, c1, s0, s1);
        tc_tab[i] = make_float2(s0 * s1, (float)clas_tgts[i]);
    }
}

// ---------------------------------------------------------------------------
// Kernel 1: anchor->target matching + smooth-L1 for positives.
// Target tables are read with wave-uniform indices -> scalar loads (SGPRs),
// no LDS. Per-block partials instead of atomics.
// grid = (ceil(A/TPB), B), block = TPB.
// ---------------------------------------------------------------------------
__global__ void match_kernel(const float*  __restrict__ bbox_preds,  // [B,A,4]
                             const float*  __restrict__ anchors,     // [A,4] cthw
                             const float4* __restrict__ ta_tab,      // [B*T]
                             const float4* __restrict__ tb_tab,      // [B*T]
                             const float2* __restrict__ tc_tab,      // [B*T]
                             int A, int T,
                             float*  __restrict__ np_p,    // [B*nblk_m]
                             float*  __restrict__ bb_p,    // [B*nblk_m]
                             int nblk_m,
                             int8_t* __restrict__ codes)   // [B*A]
{
    const int b = blockIdx.y;
    const int a = blockIdx.x * blockDim.x + threadIdx.x;
    const int img_t = b * T;
    const bool in = (a < A);

    float4 anc = make_float4(0.f, 0.f, 1.f, 1.f);
    if (in) anc = reinterpret_cast<const float4*>(anchors)[a];
    const float a_tl0 = anc.x - anc.z * 0.5f;
    const float a_tl1 = anc.y - anc.w * 0.5f;
    const float a_br0 = anc.x + anc.z * 0.5f;
    const float a_br1 = anc.y + anc.w * 0.5f;
    const float a_area = anc.z * anc.w;

    float best = -1e30f;
    int   besti = 0;

    #pragma unroll 4
    for (int t = 0; t < T; ++t) {
        const float4 ta = ta_tab[img_t + t];   // uniform -> s_load_dwordx4
        const float2 tc = tc_tab[img_t + t];   // uniform -> s_load_dwordx2
        float iou = -1.0f;
        if (tc.y > 0.f) {                      // uniform branch (padding check)
            const float tl0 = fmaxf(a_tl0, ta.x);
            const float tl1 = fmaxf(a_tl1, ta.y);
            const float br0 = fminf(a_br0, ta.z);
            const float br1 = fminf(a_br1, ta.w);
            const float sz0 = fmaxf(br0 - tl0, 0.0f);
            const float sz1 = fmaxf(br1 - tl1, 0.0f);
            const float inter = sz0 * sz1;
            const float uni = a_area + tc.x - inter;
            iou = inter / (uni + 1e-8f);
        }
        if (iou > best) { best = iou; besti = t; }  // strict > == first argmax
    }

    const bool pos = in && (best > 0.5f);
    float sl1 = 0.f;
    int   cls = 0;
    if (pos) {
        // rare path: divergent vector loads + precise logf, negligible cost
        const float2 tcb = tc_tab[img_t + besti];
        const float4 tb  = tb_tab[img_t + besti];
        cls = (int)tcb.y;
        const float4 bp = reinterpret_cast<const float4*>(bbox_preds)[(size_t)b * A + a];
        const float tc0 = (tb.x - anc.x) / anc.z;
        const float tc1 = (tb.y - anc.y) / anc.w;
        const float ts0 = logf(tb.z / anc.z + 1e-8f);
        const float ts1 = logf(tb.w / anc.w + 1e-8f);
        const float r0 = tc0 / 0.1f, r1 = tc1 / 0.1f;
        const float r2 = ts0 / 0.2f, r3 = ts1 / 0.2f;
        const float d0 = bp.x - r0, d1 = bp.y - r1, d2 = bp.z - r2, d3 = bp.w - r3;
        const float a0 = fabsf(d0), a1 = fabsf(d1), a2 = fabsf(d2), a3 = fabsf(d3);
        sl1 += (a0 < 1.f) ? 0.5f * d0 * d0 : a0 - 0.5f;
        sl1 += (a1 < 1.f) ? 0.5f * d1 * d1 : a1 - 0.5f;
        sl1 += (a2 < 1.f) ? 0.5f * d2 * d2 : a2 - 0.5f;
        sl1 += (a3 < 1.f) ? 0.5f * d3 * d3 : a3 - 0.5f;
    }

    if (in) codes[(size_t)b * A + a] =
        pos ? (int8_t)cls : ((best < 0.4f) ? (int8_t)0 : (int8_t)-1);

    // block reduction of sl1 and positive-count -> per-block partials
    float v = sl1;
    #pragma unroll
    for (int off = 32; off; off >>= 1) v += __shfl_down(v, off);
    const unsigned long long bal = __ballot(pos);

    __shared__ float s_sl1[TPB / 64];
    __shared__ int   s_np[TPB / 64];
    const int wid = threadIdx.x >> 6;
    if ((threadIdx.x & 63) == 0) { s_sl1[wid] = v; s_np[wid] = __popcll(bal); }
    __syncthreads();
    if (threadIdx.x == 0) {
        float tv = 0.f; int tn = 0;
        #pragma unroll
        for (int w = 0; w < TPB / 64; ++w) { tv += s_sl1[w]; tn += s_np[w]; }
        bb_p[(size_t)b * nblk_m + blockIdx.x] = tv;
        np_p[(size_t)b * nblk_m + blockIdx.x] = (float)tn;
    }
}

// ---------------------------------------------------------------------------
// Kernel 2: focal loss over [B, A, C], float4 along C, EPT float4s per thread.
// Hardware transcendentals (v_exp/v_log/v_rcp). Per-block partials, no atomics.
// ---------------------------------------------------------------------------
__global__ void focal_kernel(const float*  __restrict__ clas_preds,  // [B,A,C]
                             const int8_t* __restrict__ codes,       // [B*A]
                             int A, int C4,
                             float* __restrict__ partials)           // [B*gridDim.x]
{
    const int b = blockIdx.y;
    const unsigned tot  = (unsigned)A * (unsigned)C4;
    const unsigned base = blockIdx.x * (TPB * EPT) + threadIdx.x;
    const size_t img_off = (size_t)b * A;

    float local = 0.f;
    #pragma unroll
    for (int k = 0; k < EPT; ++k) {
        const unsigned e = base + (unsigned)k * TPB;
        if (e < tot) {
            const unsigned a  = e / (unsigned)C4;   // 32-bit magic-mul div
            const unsigned c4 = e - a * (unsigned)C4;
            const int code = codes[img_off + a];
            if (code >= 0) {  // not ignored
                const float4 x4 =
                    reinterpret_cast<const float4*>(clas_preds)[(img_off + a) * C4 + c4];
                const int target = code - 1;  // -1 => background (no one-hot hit)
                const float xs[4] = {x4.x, x4.y, x4.z, x4.w};
                #pragma unroll
                for (int j = 0; j < 4; ++j) {
                    const float x  = xs[j];
                    const float ax = fabsf(x);
                    const float em = __builtin_amdgcn_exp2f(ax * -1.44269504089f);
                    const float one_em = 1.f + em;
                    const float l = __builtin_amdgcn_logf(one_em) * 0.69314718056f;
                    const float s = __builtin_amdgcn_rcpf(one_em);   // sigmoid(|x|)
                    const bool nonneg = (x >= 0.f);
                    const float sp_p = nonneg ? (x + l) : l;   // softplus(x)
                    const float sp_n = sp_p - x;               // softplus(-x)
                    const float p  = nonneg ? s : (1.f - s);   // sigmoid(x)
                    const float q  = 1.f - p;
                    const bool enc = ((int)(c4 * 4 + j) == target);
                    local += enc ? (0.75f * q * q * sp_n)
                                 : (0.25f * p * p * sp_p);
                }
            }
        }
    }

    float v = local;
    #pragma unroll
    for (int off = 32; off; off >>= 1) v += __shfl_down(v, off);
    __shared__ float s_w[TPB / 64];
    const int wid = threadIdx.x >> 6;
    if ((threadIdx.x & 63) == 0) s_w[wid] = v;
    __syncthreads();
    if (threadIdx.x == 0) {
        float tv = 0.f;
        #pragma unroll
        for (int w = 0; w < TPB / 64; ++w) tv += s_w[w];
        partials[(size_t)b * gridDim.x + blockIdx.x] = tv;
    }
}

// ---------------------------------------------------------------------------
// Kernel 3: fused final reduce. One wave per image; wave 0 makes the scalar.
// block = 1024 threads (16 waves).
// ---------------------------------------------------------------------------
__global__ void reduce_kernel(const float* __restrict__ partials, // [B*nblk_f]
                              int nblk_f,
                              const float* __restrict__ np_p,     // [B*nblk_m]
                              const float* __restrict__ bb_p,     // [B*nblk_m]
                              int nblk_m,
                              int Bn, float* __restrict__ out)
{
    const int wid  = threadIdx.x >> 6;
    const int lane = threadIdx.x & 63;
    const int nw   = blockDim.x >> 6;
    __shared__ float s_loss[32];

    float acc = 0.f;
    for (int b = wid; b < Bn; b += nw) {
        float cl = 0.f, bb = 0.f, np = 0.f;
        for (int i = lane; i < nblk_f; i += 64)
            cl += partials[(size_t)b * nblk_f + i];
        for (int i = lane; i < nblk_m; i += 64) {
            np += np_p[(size_t)b * nblk_m + i];
            bb += bb_p[(size_t)b * nblk_m + i];
        }
        #pragma unroll
        for (int off = 32; off; off >>= 1) {
            cl += __shfl_down(cl, off);
            bb += __shfl_down(bb, off);
            np += __shfl_down(np, off);
        }
        if (lane == 0)
            acc += bb / fmaxf(4.f * np, 1.f) + cl / fmaxf(np, 1.f);
    }
    if (lane == 0) s_loss[wid] = acc;
    __syncthreads();
    if (threadIdx.x == 0) {
        float v = 0.f;
        for (int w = 0; w < nw; ++w) v += s_loss[w];
        out[0] = v / (float)Bn;
    }
}

// ---------------------------------------------------------------------------
extern "C" void kernel_launch(void* const* d_in, const int* in_sizes, int n_in,
                              void* d_out, int out_size, void* d_ws, size_t ws_size,
                              hipStream_t stream)
{
    const float* clas_preds = (const float*)d_in[0];
    const float* bbox_preds = (const float*)d_in[1];
    const float* bbox_tgts  = (const float*)d_in[2];
    const int*   clas_tgts  = (const int*)d_in[3];
    const float* anchors    = (const float*)d_in[4];

    const int A  = in_sizes[4] / 4;
    const int Bn = in_sizes[1] / (A * 4);
    const int T  = in_sizes[3] / Bn;
    const int C  = in_sizes[0] / (Bn * A);
    const int C4 = C / 4;
    const int BT = Bn * T;

    const unsigned tot    = (unsigned)A * (unsigned)C4;
    const unsigned nblk_f = (tot + TPB * EPT - 1) / (TPB * EPT);
    const unsigned nblk_m = (unsigned)((A + TPB - 1) / TPB);

    // workspace layout (alignment-descending):
    // ta_tab f4[BT] | tb_tab f4[BT] | tc_tab f2[BT] |
    // partials f[B*nblk_f] | np_p f[B*nblk_m] | bb_p f[B*nblk_m] | codes i8[B*A]
    char* ws = (char*)d_ws;
    float4* ta_tab   = (float4*)ws;  ws += (size_t)BT * sizeof(float4);
    float4* tb_tab   = (float4*)ws;  ws += (size_t)BT * sizeof(float4);
    float2* tc_tab   = (float2*)ws;  ws += (size_t)BT * sizeof(float2);
    float*  partials = (float*)ws;   ws += (size_t)Bn * nblk_f * sizeof(float);
    float*  np_p     = (float*)ws;   ws += (size_t)Bn * nblk_m * sizeof(float);
    float*  bb_p     = (float*)ws;   ws += (size_t)Bn * nblk_m * sizeof(float);
    int8_t* codes    = (int8_t*)ws;

    prep_kernel<<<(BT + TPB - 1) / TPB, TPB, 0, stream>>>(
        bbox_tgts, clas_tgts, BT, ta_tab, tb_tab, tc_tab);

    dim3 g1(nblk_m, (unsigned)Bn);
    match_kernel<<<g1, TPB, 0, stream>>>(bbox_preds, anchors, ta_tab, tb_tab, tc_tab,
                                         A, T, np_p, bb_p, (int)nblk_m, codes);

    dim3 g2(nblk_f, (unsigned)Bn);
    focal_kernel<<<g2, TPB, 0, stream>>>(clas_preds, codes, A, C4, partials);

    reduce_kernel<<<1, 1024, 0, stream>>>(partials, (int)nblk_f,
                                          np_p, bb_p, (int)nblk_m,
                                          Bn, (float*)d_out);
}

// Round 5
// 96.915 us; speedup vs baseline: 1.0933x; 1.0933x over previous
//
#include <hip/hip_runtime.h>
#include <cstdint>
#include <cstddef>

#define TPB 256
#define EPT 8             // float4s per thread in focal kernel

// f_bg(x) = 0.25 * sigmoid(x)^2 * softplus(x)   (background / enc=0 term)
// f_fg(x) = 0.75 * (1-sigmoid(x))^2 * softplus(-x)  (target / enc=1 term)
// Both from one exp2 + one log + one rcp (hardware transcendentals).
__device__ __forceinline__ float f_bg(float x) {
    const float ax = fabsf(x);
    const float em = __builtin_amdgcn_exp2f(ax * -1.44269504089f);  // e^-|x|
    const float oe = 1.f + em;
    const float l  = __builtin_amdgcn_logf(oe) * 0.69314718056f;    // softplus(-|x|)
    const float s  = __builtin_amdgcn_rcpf(oe);                     // sigmoid(|x|)
    const float sp = (x >= 0.f) ? (x + l) : l;                      // softplus(x)
    const float p  = (x >= 0.f) ? s : (1.f - s);                    // sigmoid(x)
    return 0.25f * p * p * sp;
}
__device__ __forceinline__ float f_fg_minus_bg(float x) {
    const float ax = fabsf(x);
    const float em = __builtin_amdgcn_exp2f(ax * -1.44269504089f);
    const float oe = 1.f + em;
    const float l  = __builtin_amdgcn_logf(oe) * 0.69314718056f;
    const float s  = __builtin_amdgcn_rcpf(oe);
    const float sp_p = (x >= 0.f) ? (x + l) : l;
    const float sp_n = sp_p - x;
    const float p  = (x >= 0.f) ? s : (1.f - s);
    const float q  = 1.f - p;
    return 0.75f * q * q * sp_n - 0.25f * p * p * sp_p;
}

// ---------------------------------------------------------------------------
// Kernel 0: prep per-image target tables (B*T entries, trivial).
// ta = (tl0,tl1,br0,br1), tb = (c0,c1,s0,s1), tc = (area, cls_as_float)
// ---------------------------------------------------------------------------
__global__ void prep_kernel(const float* __restrict__ bbox_tgts,  // [B,T,4] tlbr
                            const int*   __restrict__ clas_tgts,  // [B,T]
                            int BT,
                            float4* __restrict__ ta_tab,
                            float4* __restrict__ tb_tab,
                            float2* __restrict__ tc_tab)
{
    const int i = blockIdx.x * blockDim.x + threadIdx.x;
    if (i < BT) {
        const float4 tg = reinterpret_cast<const float4*>(bbox_tgts)[i];
        const float c0 = (tg.x + tg.z) * 0.5f, c1 = (tg.y + tg.w) * 0.5f;
        const float s0 = tg.z - tg.x,          s1 = tg.w - tg.y;
        ta_tab[i] = make_float4(c0 - s0 * 0.5f, c1 - s1 * 0.5f,
                                c0 + s0 * 0.5f, c1 + s1 * 0.5f);
        tb_tab[i] = make_float4(c0, c1, s0, s1);
        tc_tab[i] = make_float2(s0 * s1, (float)clas_tgts[i]);
    }
}

// ---------------------------------------------------------------------------
// Kernel 1: matching + smooth-L1 + SPARSE focal corrections.
// Per block of 256 anchors: compact positive & ignored anchors via
// ballot/prefix (deterministic), then block-cooperatively compute
//   +[f_fg - f_bg](x_target)  for positives  (1 float each)
//   -sum_c f_bg(x_c)          for ignored    (C floats each)
// No codes buffer, no device atomics.
// ---------------------------------------------------------------------------
__global__ void match_kernel(const float*  __restrict__ bbox_preds,  // [B,A,4]
                             const float*  __restrict__ anchors,     // [A,4] cthw
                             const float*  __restrict__ clas_preds,  // [B,A,C]
                             const float4* __restrict__ ta_tab,      // [B*T]
                             const float4* __restrict__ tb_tab,      // [B*T]
                             const float2* __restrict__ tc_tab,      // [B*T]
                             int A, int T, int C,
                             float* __restrict__ np_p,    // [B*nblk_m]
                             float* __restrict__ bb_p,    // [B*nblk_m]
                             float* __restrict__ cl_p,    // [B*nblk_m]
                             int nblk_m)
{
    const int b = blockIdx.y;
    const int a = blockIdx.x * blockDim.x + threadIdx.x;
    const int img_t = b * T;
    const bool in = (a < A);
    const int C4 = C >> 2;

    float4 anc = make_float4(0.f, 0.f, 1.f, 1.f);
    if (in) anc = reinterpret_cast<const float4*>(anchors)[a];
    const float a_tl0 = anc.x - anc.z * 0.5f;
    const float a_tl1 = anc.y - anc.w * 0.5f;
    const float a_br0 = anc.x + anc.z * 0.5f;
    const float a_br1 = anc.y + anc.w * 0.5f;
    const float a_area = anc.z * anc.w;

    float best = -1e30f;
    int   besti = 0;

    #pragma unroll 4
    for (int t = 0; t < T; ++t) {
        const float4 ta = ta_tab[img_t + t];   // uniform -> scalar loads
        const float2 tc = tc_tab[img_t + t];
        float iou = -1.0f;
        if (tc.y > 0.f) {
            const float tl0 = fmaxf(a_tl0, ta.x);
            const float tl1 = fmaxf(a_tl1, ta.y);
            const float br0 = fminf(a_br0, ta.z);
            const float br1 = fminf(a_br1, ta.w);
            const float sz0 = fmaxf(br0 - tl0, 0.0f);
            const float sz1 = fmaxf(br1 - tl1, 0.0f);
            const float inter = sz0 * sz1;
            const float uni = a_area + tc.x - inter;
            iou = inter / (uni + 1e-8f);
        }
        if (iou > best) { best = iou; besti = t; }  // strict > == first argmax
    }

    const bool pos = in && (best > 0.5f);
    const bool ign = in && !pos && !(best < 0.4f);   // 0.4 <= iou <= 0.5

    float sl1 = 0.f;
    int   cls = 0;
    if (pos) {
        const float2 tcb = tc_tab[img_t + besti];
        const float4 tb  = tb_tab[img_t + besti];
        cls = (int)tcb.y;
        const float4 bp = reinterpret_cast<const float4*>(bbox_preds)[(size_t)b * A + a];
        const float tc0 = (tb.x - anc.x) / anc.z;
        const float tc1 = (tb.y - anc.y) / anc.w;
        const float ts0 = logf(tb.z / anc.z + 1e-8f);
        const float ts1 = logf(tb.w / anc.w + 1e-8f);
        const float r0 = tc0 / 0.1f, r1 = tc1 / 0.1f;
        const float r2 = ts0 / 0.2f, r3 = ts1 / 0.2f;
        const float d0 = bp.x - r0, d1 = bp.y - r1, d2 = bp.z - r2, d3 = bp.w - r3;
        const float a0 = fabsf(d0), a1 = fabsf(d1), a2 = fabsf(d2), a3 = fabsf(d3);
        sl1 += (a0 < 1.f) ? 0.5f * d0 * d0 : a0 - 0.5f;
        sl1 += (a1 < 1.f) ? 0.5f * d1 * d1 : a1 - 0.5f;
        sl1 += (a2 < 1.f) ? 0.5f * d2 * d2 : a2 - 0.5f;
        sl1 += (a3 < 1.f) ? 0.5f * d3 * d3 : a3 - 0.5f;
    }

    // ---- deterministic compaction of positives / ignored ----
    const int lane = threadIdx.x & 63;
    const int wid  = threadIdx.x >> 6;
    const unsigned long long pball = __ballot(pos);
    const unsigned long long iball = __ballot(ign);

    __shared__ int s_pc[TPB / 64], s_ic[TPB / 64];
    __shared__ int s_plist[TPB], s_pcls[TPB], s_ilist[TPB];
    if (lane == 0) { s_pc[wid] = __popcll(pball); s_ic[wid] = __popcll(iball); }
    __syncthreads();
    int p_off = 0, i_off = 0, p_total = 0, i_total = 0;
    #pragma unroll
    for (int w = 0; w < TPB / 64; ++w) {
        if (w < wid) { p_off += s_pc[w]; i_off += s_ic[w]; }
        p_total += s_pc[w]; i_total += s_ic[w];
    }
    const unsigned long long lmask = (lane == 63) ? ~0ULL >> 1 : (1ULL << lane) - 1;
    if (pos) {
        const int idx = p_off + __popcll(pball & lmask);
        s_plist[idx] = a; s_pcls[idx] = cls;
    }
    if (ign) {
        const int idx = i_off + __popcll(iball & lmask);
        s_ilist[idx] = a;
    }
    __syncthreads();

    // ---- block-cooperative sparse corrections ----
    float corr = 0.f;
    if (threadIdx.x < p_total) {
        const int pa = s_plist[threadIdx.x];
        const int pc = s_pcls[threadIdx.x];
        const float x = clas_preds[((size_t)b * A + pa) * C + (pc - 1)];
        corr += f_fg_minus_bg(x);
    }
    const int ig_elems = i_total * C4;
    for (int j = threadIdx.x; j < ig_elems; j += TPB) {
        const int ii = j / C4;
        const int c4 = j - ii * C4;
        const int ia = s_ilist[ii];
        const float4 x4 = reinterpret_cast<const float4*>(clas_preds)
                              [((size_t)b * A + ia) * C4 + c4];
        corr -= f_bg(x4.x) + f_bg(x4.y) + f_bg(x4.z) + f_bg(x4.w);
    }

    // ---- block reduction: sl1, corr (floats) + npos (ballot counts) ----
    float v = sl1, u = corr;
    #pragma unroll
    for (int off = 32; off; off >>= 1) {
        v += __shfl_down(v, off);
        u += __shfl_down(u, off);
    }
    __shared__ float s_sl1[TPB / 64], s_co[TPB / 64];
    if (lane == 0) { s_sl1[wid] = v; s_co[wid] = u; }
    __syncthreads();
    if (threadIdx.x == 0) {
        float tv = 0.f, tu = 0.f;
        #pragma unroll
        for (int w = 0; w < TPB / 64; ++w) { tv += s_sl1[w]; tu += s_co[w]; }
        const size_t o = (size_t)b * nblk_m + blockIdx.x;
        bb_p[o] = tv;
        cl_p[o] = tu;
        np_p[o] = (float)p_total;
    }
}

// ---------------------------------------------------------------------------
// Kernel 2: dense background focal sum over [B, A*C]: branch-free coalesced
// reduction, no lookups. grid = (nblk_f, B).
// ---------------------------------------------------------------------------
__global__ void focal_kernel(const float4* __restrict__ cp4,   // [B, A*C4]
                             unsigned tot4,                    // A*C4
                             float* __restrict__ partials)     // [B*gridDim.x]
{
    const int b = blockIdx.y;
    const unsigned base = blockIdx.x * (TPB * EPT) + threadIdx.x;
    const float4* img = cp4 + (size_t)b * tot4;

    float local = 0.f;
    #pragma unroll
    for (int k = 0; k < EPT; ++k) {
        const unsigned e = base + (unsigned)k * TPB;
        if (e < tot4) {
            const float4 x4 = img[e];
            local += f_bg(x4.x) + f_bg(x4.y) + f_bg(x4.z) + f_bg(x4.w);
        }
    }

    float v = local;
    #pragma unroll
    for (int off = 32; off; off >>= 1) v += __shfl_down(v, off);
    __shared__ float s_w[TPB / 64];
    const int wid = threadIdx.x >> 6;
    if ((threadIdx.x & 63) == 0) s_w[wid] = v;
    __syncthreads();
    if (threadIdx.x == 0) {
        float tv = 0.f;
        #pragma unroll
        for (int w = 0; w < TPB / 64; ++w) tv += s_w[w];
        partials[(size_t)b * gridDim.x + blockIdx.x] = tv;
    }
}

// ---------------------------------------------------------------------------
// Kernel 3: fused final reduce. One wave per image; thread 0 emits scalar.
// ---------------------------------------------------------------------------
__global__ void reduce_kernel(const float* __restrict__ partials, // [B*nblk_f]
                              int nblk_f,
                              const float* __restrict__ np_p,     // [B*nblk_m]
                              const float* __restrict__ bb_p,     // [B*nblk_m]
                              const float* __restrict__ cl_p,     // [B*nblk_m]
                              int nblk_m,
                              int Bn, float* __restrict__ out)
{
    const int wid  = threadIdx.x >> 6;
    const int lane = threadIdx.x & 63;
    const int nw   = blockDim.x >> 6;
    __shared__ float s_loss[32];

    float acc = 0.f;
    for (int b = wid; b < Bn; b += nw) {
        float cl = 0.f, bb = 0.f, np = 0.f;
        for (int i = lane; i < nblk_f; i += 64)
            cl += partials[(size_t)b * nblk_f + i];
        for (int i = lane; i < nblk_m; i += 64) {
            np += np_p[(size_t)b * nblk_m + i];
            bb += bb_p[(size_t)b * nblk_m + i];
            cl += cl_p[(size_t)b * nblk_m + i];
        }
        #pragma unroll
        for (int off = 32; off; off >>= 1) {
            cl += __shfl_down(cl, off);
            bb += __shfl_down(bb, off);
            np += __shfl_down(np, off);
        }
        if (lane == 0)
            acc += bb / fmaxf(4.f * np, 1.f) + cl / fmaxf(np, 1.f);
    }
    if (lane == 0) s_loss[wid] = acc;
    __syncthreads();
    if (threadIdx.x == 0) {
        float v = 0.f;
        for (int w = 0; w < nw; ++w) v += s_loss[w];
        out[0] = v / (float)Bn;
    }
}

// ---------------------------------------------------------------------------
extern "C" void kernel_launch(void* const* d_in, const int* in_sizes, int n_in,
                              void* d_out, int out_size, void* d_ws, size_t ws_size,
                              hipStream_t stream)
{
    const float* clas_preds = (const float*)d_in[0];
    const float* bbox_preds = (const float*)d_in[1];
    const float* bbox_tgts  = (const float*)d_in[2];
    const int*   clas_tgts  = (const int*)d_in[3];
    const float* anchors    = (const float*)d_in[4];

    const int A  = in_sizes[4] / 4;
    const int Bn = in_sizes[1] / (A * 4);
    const int T  = in_sizes[3] / Bn;
    const int C  = in_sizes[0] / (Bn * A);
    const int C4 = C / 4;
    const int BT = Bn * T;

    const unsigned tot4   = (unsigned)A * (unsigned)C4;
    const unsigned nblk_f = (tot4 + TPB * EPT - 1) / (TPB * EPT);
    const unsigned nblk_m = (unsigned)((A + TPB - 1) / TPB);

    // workspace: ta f4[BT] | tb f4[BT] | tc f2[BT] |
    //            partials f[B*nblk_f] | np_p | bb_p | cl_p  f[B*nblk_m] each
    char* ws = (char*)d_ws;
    float4* ta_tab   = (float4*)ws;  ws += (size_t)BT * sizeof(float4);
    float4* tb_tab   = (float4*)ws;  ws += (size_t)BT * sizeof(float4);
    float2* tc_tab   = (float2*)ws;  ws += (size_t)BT * sizeof(float2);
    float*  partials = (float*)ws;   ws += (size_t)Bn * nblk_f * sizeof(float);
    float*  np_p     = (float*)ws;   ws += (size_t)Bn * nblk_m * sizeof(float);
    float*  bb_p     = (float*)ws;   ws += (size_t)Bn * nblk_m * sizeof(float);
    float*  cl_p     = (float*)ws;

    prep_kernel<<<(BT + TPB - 1) / TPB, TPB, 0, stream>>>(
        bbox_tgts, clas_tgts, BT, ta_tab, tb_tab, tc_tab);

    dim3 g1(nblk_m, (unsigned)Bn);
    match_kernel<<<g1, TPB, 0, stream>>>(bbox_preds, anchors, clas_preds,
                                         ta_tab, tb_tab, tc_tab,
                                         A, T, C, np_p, bb_p, cl_p, (int)nblk_m);

    dim3 g2(nblk_f, (unsigned)Bn);
    focal_kernel<<<g2, TPB, 0, stream>>>(
        reinterpret_cast<const float4*>(clas_preds), tot4, partials);

    reduce_kernel<<<1, 1024, 0, stream>>>(partials, (int)nblk_f,
                                          np_p, bb_p, cl_p, (int)nblk_m,
                                          Bn, (float*)d_out);
}

// Round 6
// 80.446 us; speedup vs baseline: 1.3171x; 1.2047x over previous
//
#include <hip/hip_runtime.h>
#include <cstdint>
#include <cstddef>

#define TPB 256
#define MAXT 128   // max targets stageable in LDS (T=64 here)

// f_bg(x) = 0.25 * sigmoid(x)^2 * softplus(x)       (background / enc=0 term)
// f_fg(x) = 0.75 * (1-sigmoid(x))^2 * softplus(-x)  (target / enc=1 term)
// One hw exp2 + one hw log + one hw rcp each.
__device__ __forceinline__ float f_bg(float x) {
    const float ax = fabsf(x);
    const float em = __builtin_amdgcn_exp2f(ax * -1.44269504089f);  // e^-|x|
    const float oe = 1.f + em;
    const float l  = __builtin_amdgcn_logf(oe) * 0.69314718056f;    // softplus(-|x|)
    const float s  = __builtin_amdgcn_rcpf(oe);                     // sigmoid(|x|)
    const float sp = (x >= 0.f) ? (x + l) : l;                      // softplus(x)
    const float p  = (x >= 0.f) ? s : (1.f - s);                    // sigmoid(x)
    return 0.25f * p * p * sp;
}
__device__ __forceinline__ float f_fg_minus_bg(float x) {
    const float ax = fabsf(x);
    const float em = __builtin_amdgcn_exp2f(ax * -1.44269504089f);
    const float oe = 1.f + em;
    const float l  = __builtin_amdgcn_logf(oe) * 0.69314718056f;
    const float s  = __builtin_amdgcn_rcpf(oe);
    const float sp_p = (x >= 0.f) ? (x + l) : l;
    const float sp_n = sp_p - x;
    const float p  = (x >= 0.f) ? s : (1.f - s);
    const float q  = 1.f - p;
    return 0.75f * q * q * sp_n - 0.25f * p * p * sp_p;
}

// ---------------------------------------------------------------------------
// Fused kernel: per block = 256 contiguous anchors of one image.
//   phase 0: stage 64 targets into LDS
//   phase 1: match (IoU max/argmax) -> code per anchor in LDS; smooth-L1 for pos
//   phase 2: focal sum over this block's [256 x C] class-pred tile
//            (dense f_bg for code>=0 anchors, skip ignored, +fix for positives)
//   phase 3: block reduce -> (npos, bb, cl) partials.   No atomics anywhere.
// grid = (ceil(A/TPB), B), block = TPB.
// ---------------------------------------------------------------------------
__global__ void fused_kernel(const float* __restrict__ bbox_preds,  // [B,A,4]
                             const float* __restrict__ bbox_tgts,   // [B,T,4] tlbr
                             const int*   __restrict__ clas_tgts,   // [B,T]
                             const float* __restrict__ anchors,     // [A,4] cthw
                             const float* __restrict__ clas_preds,  // [B,A,C]
                             int A, int T, int C,
                             float* __restrict__ np_p,   // [B*nblk]
                             float* __restrict__ bb_p,   // [B*nblk]
                             float* __restrict__ cl_p,   // [B*nblk]
                             int nblk)
{
    const int b   = blockIdx.y;
    const int a0  = blockIdx.x * TPB;
    const int tid = threadIdx.x;
    const int a   = a0 + tid;
    const int C4  = C >> 2;

    // ---- phase 0: stage targets ----
    __shared__ float t_tl0[MAXT], t_tl1[MAXT], t_br0[MAXT], t_br1[MAXT];
    __shared__ float t_area[MAXT];
    __shared__ float t_c0[MAXT], t_c1[MAXT], t_s0[MAXT], t_s1[MAXT];
    __shared__ int   t_cls[MAXT];
    for (int i = tid; i < T; i += TPB) {
        const float4 tg = reinterpret_cast<const float4*>(bbox_tgts)[(size_t)b * T + i];
        const float c0 = (tg.x + tg.z) * 0.5f, c1 = (tg.y + tg.w) * 0.5f;
        const float s0 = tg.z - tg.x,          s1 = tg.w - tg.y;
        t_c0[i] = c0; t_c1[i] = c1; t_s0[i] = s0; t_s1[i] = s1;
        t_tl0[i] = c0 - s0 * 0.5f; t_tl1[i] = c1 - s1 * 0.5f;
        t_br0[i] = c0 + s0 * 0.5f; t_br1[i] = c1 + s1 * 0.5f;
        t_area[i] = s0 * s1;
        t_cls[i]  = clas_tgts[(size_t)b * T + i];
    }
    __syncthreads();

    // ---- phase 1: match ----
    const bool in = (a < A);
    float4 anc = make_float4(0.f, 0.f, 1.f, 1.f);
    if (in) anc = reinterpret_cast<const float4*>(anchors)[a];
    const float a_tl0 = anc.x - anc.z * 0.5f;
    const float a_tl1 = anc.y - anc.w * 0.5f;
    const float a_br0 = anc.x + anc.z * 0.5f;
    const float a_br1 = anc.y + anc.w * 0.5f;
    const float a_area = anc.z * anc.w;

    float best = -1e30f;
    int   besti = 0;
    #pragma unroll 4
    for (int t = 0; t < T; ++t) {
        float iou = -1.0f;
        if (t_cls[t] > 0) {                       // wave-uniform branch
            const float tl0 = fmaxf(a_tl0, t_tl0[t]);
            const float tl1 = fmaxf(a_tl1, t_tl1[t]);
            const float br0 = fminf(a_br0, t_br0[t]);
            const float br1 = fminf(a_br1, t_br1[t]);
            const float sz0 = fmaxf(br0 - tl0, 0.0f);
            const float sz1 = fmaxf(br1 - tl1, 0.0f);
            const float inter = sz0 * sz1;
            const float uni = a_area + t_area[t] - inter;
            iou = inter / (uni + 1e-8f);
        }
        if (iou > best) { best = iou; besti = t; }  // strict > == first argmax
    }

    const bool pos = in && (best > 0.5f);
    const bool ign = in && !pos && !(best < 0.4f);  // 0.4 <= iou <= 0.5

    float sl1 = 0.f;
    int   cls = 0;
    if (pos) {
        // rare path: precise logf, divergent loads — negligible
        cls = t_cls[besti];
        const float4 bp = reinterpret_cast<const float4*>(bbox_preds)[(size_t)b * A + a];
        const float tc0 = (t_c0[besti] - anc.x) / anc.z;
        const float tc1 = (t_c1[besti] - anc.y) / anc.w;
        const float ts0 = logf(t_s0[besti] / anc.z + 1e-8f);
        const float ts1 = logf(t_s1[besti] / anc.w + 1e-8f);
        const float r0 = tc0 / 0.1f, r1 = tc1 / 0.1f;
        const float r2 = ts0 / 0.2f, r3 = ts1 / 0.2f;
        const float d0 = bp.x - r0, d1 = bp.y - r1, d2 = bp.z - r2, d3 = bp.w - r3;
        const float a0f = fabsf(d0), a1f = fabsf(d1), a2f = fabsf(d2), a3f = fabsf(d3);
        sl1 += (a0f < 1.f) ? 0.5f * d0 * d0 : a0f - 0.5f;
        sl1 += (a1f < 1.f) ? 0.5f * d1 * d1 : a1f - 0.5f;
        sl1 += (a2f < 1.f) ? 0.5f * d2 * d2 : a2f - 0.5f;
        sl1 += (a3f < 1.f) ? 0.5f * d3 * d3 : a3f - 0.5f;
    }

    // codes into LDS + deterministic compaction of positives
    __shared__ int s_code[TPB];
    __shared__ int s_pc[TPB / 64];
    __shared__ int s_plist[TPB], s_pcls[TPB];
    s_code[tid] = pos ? cls : (ign ? -1 : 0);

    const int lane = tid & 63;
    const int wid  = tid >> 6;
    const unsigned long long pball = __ballot(pos);
    if (lane == 0) s_pc[wid] = __popcll(pball);
    __syncthreads();
    int p_off = 0, p_total = 0;
    #pragma unroll
    for (int w = 0; w < TPB / 64; ++w) {
        if (w < wid) p_off += s_pc[w];
        p_total += s_pc[w];
    }
    if (pos) {
        const unsigned long long lmask = (lane == 63) ? ~0ULL >> 1 : (1ULL << lane) - 1;
        const int idx = p_off + __popcll(pball & lmask);
        s_plist[idx] = a; s_pcls[idx] = cls;
    }
    __syncthreads();

    // ---- phase 2: focal over this block's [nA x C4] float4 tile ----
    const int nA  = min(TPB, A - a0);
    const int tot = nA * C4;
    const float4* tile = reinterpret_cast<const float4*>(clas_preds)
                         + ((size_t)b * A + a0) * C4;

    int al = tid / C4;            // one runtime div, then incremental
    int c4 = tid - al * C4;
    const int qs = TPB / C4, rs = TPB - (TPB / C4) * C4;

    float facc = 0.f;
    for (int j = tid; j < tot; j += TPB) {
        const int code = s_code[al];              // mostly-broadcast LDS read
        if (code >= 0) {                          // skip ignored anchors entirely
            const float4 x4 = tile[j];
            facc += f_bg(x4.x) + f_bg(x4.y) + f_bg(x4.z) + f_bg(x4.w);
        }
        al += qs; c4 += rs;
        if (c4 >= C4) { c4 -= C4; al += 1; }
    }
    // one-element fix for each positive anchor
    if (tid < p_total) {
        const int pa = s_plist[tid];
        const int pc = s_pcls[tid];
        const float x = clas_preds[((size_t)b * A + pa) * C + (pc - 1)];
        facc += f_fg_minus_bg(x);
    }

    // ---- phase 3: block reduction -> partials ----
    float v = sl1, u = facc;
    #pragma unroll
    for (int off = 32; off; off >>= 1) {
        v += __shfl_down(v, off);
        u += __shfl_down(u, off);
    }
    __shared__ float s_sl1[TPB / 64], s_cl[TPB / 64];
    if (lane == 0) { s_sl1[wid] = v; s_cl[wid] = u; }
    __syncthreads();
    if (tid == 0) {
        float tv = 0.f, tu = 0.f;
        #pragma unroll
        for (int w = 0; w < TPB / 64; ++w) { tv += s_sl1[w]; tu += s_cl[w]; }
        const size_t o = (size_t)b * nblk + blockIdx.x;
        bb_p[o] = tv;
        cl_p[o] = tu;
        np_p[o] = (float)p_total;
    }
}

// ---------------------------------------------------------------------------
// Final reduce: one wave per image, thread 0 emits the scalar.
// ---------------------------------------------------------------------------
__global__ void reduce_kernel(const float* __restrict__ np_p,  // [B*nblk]
                              const float* __restrict__ bb_p,
                              const float* __restrict__ cl_p,
                              int nblk, int Bn,
                              float* __restrict__ out)
{
    const int wid  = threadIdx.x >> 6;
    const int lane = threadIdx.x & 63;
    const int nw   = blockDim.x >> 6;
    __shared__ float s_loss[32];

    float acc = 0.f;
    for (int b = wid; b < Bn; b += nw) {
        float cl = 0.f, bb = 0.f, np = 0.f;
        for (int i = lane; i < nblk; i += 64) {
            const size_t o = (size_t)b * nblk + i;
            np += np_p[o]; bb += bb_p[o]; cl += cl_p[o];
        }
        #pragma unroll
        for (int off = 32; off; off >>= 1) {
            cl += __shfl_down(cl, off);
            bb += __shfl_down(bb, off);
            np += __shfl_down(np, off);
        }
        if (lane == 0)
            acc += bb / fmaxf(4.f * np, 1.f) + cl / fmaxf(np, 1.f);
    }
    if (lane == 0) s_loss[wid] = acc;
    __syncthreads();
    if (threadIdx.x == 0) {
        float v = 0.f;
        for (int w = 0; w < nw; ++w) v += s_loss[w];
        out[0] = v / (float)Bn;
    }
}

// ---------------------------------------------------------------------------
extern "C" void kernel_launch(void* const* d_in, const int* in_sizes, int n_in,
                              void* d_out, int out_size, void* d_ws, size_t ws_size,
                              hipStream_t stream)
{
    const float* clas_preds = (const float*)d_in[0];
    const float* bbox_preds = (const float*)d_in[1];
    const float* bbox_tgts  = (const float*)d_in[2];
    const int*   clas_tgts  = (const int*)d_in[3];
    const float* anchors    = (const float*)d_in[4];

    const int A  = in_sizes[4] / 4;
    const int Bn = in_sizes[1] / (A * 4);
    const int T  = in_sizes[3] / Bn;
    const int C  = in_sizes[0] / (Bn * A);

    const int nblk = (A + TPB - 1) / TPB;

    // workspace: np_p | bb_p | cl_p, each float[B*nblk]
    char* ws = (char*)d_ws;
    float* np_p = (float*)ws;  ws += (size_t)Bn * nblk * sizeof(float);
    float* bb_p = (float*)ws;  ws += (size_t)Bn * nblk * sizeof(float);
    float* cl_p = (float*)ws;

    dim3 g1((unsigned)nblk, (unsigned)Bn);
    fused_kernel<<<g1, TPB, 0, stream>>>(bbox_preds, bbox_tgts, clas_tgts, anchors,
                                         clas_preds, A, T, C,
                                         np_p, bb_p, cl_p, nblk);

    reduce_kernel<<<1, 1024, 0, stream>>>(np_p, bb_p, cl_p, nblk, Bn, (float*)d_out);
}